// Round 11
// baseline (291.201 us; speedup 1.0000x reference)
//
#include <hip/hip_runtime.h>

// LSTM forecast: B=1024, S=512, I=1, H=50.
// R11: R7 per-wave structure (fdot2 + LDS-broadcast h, lowest measured VALU
// busy = ~534 cyc/step) x OCCUPANCY fix. R10's hand-asm proved the kernel is
// latency-bound at 1 wave/SIMD (minimal stream -> still ~1030 cyc/step, 73%
// busy): dot2 is half-rate (= FP32-peak MACs), so the matmul floor is ~400
// cyc and the win is filling the ~300-400 stall cycles. 1024 waves always
// spread 1/SIMD -- UNLESS a block has 8 waves (must share one CU's 4 SIMDs).
// So: 128 blocks x 512 threads; each of the 8 waves = one full batch,
// fully independent (no barriers, per-wave LDS slice). Sibling waves are
// phase-drifted and fill each other's dependency/LDS/trans stalls.
// waves_per_eu(2,2) -> 256-VGPR budget; R7's 132 fits with headroom.

typedef _Float16 half2v __attribute__((ext_vector_type(2)));

#define LOG2E 1.44269504088896340736f
#define B_ 1024
#define S_ 512
#define H_ 50
#define WPB 8   // waves per block

__device__ __forceinline__ float rcp_(float x) { return __builtin_amdgcn_rcpf(x); }
__device__ __forceinline__ float ex2_(float x) { return __builtin_amdgcn_exp2f(x); }

// Pack W_hh into [gate][pair m][lane] f16-pairs, pre-scaled by activation
// log2 factors (i,f,o: -log2e ; g: +2*log2e). Also pre-scale W_ih and biases.
__global__ void lstm_pack(const float* __restrict__ W_ih, const float* __restrict__ W_hh,
                          const float* __restrict__ b_ih, const float* __restrict__ b_hh,
                          unsigned* __restrict__ wpk, float* __restrict__ wih_pk,
                          float* __restrict__ bias_pk)
{
    int tid = blockIdx.x * blockDim.x + threadIdx.x;
    int stride = blockDim.x * gridDim.x;
    for (int p = tid; p < 4 * 25 * 64; p += stride) {
        int j = p & 63;
        int m = (p >> 6) % 25;
        int g = p / (25 * 64);
        float s = (g == 2) ? (2.0f * LOG2E) : (-LOG2E);
        float a = 0.0f, bb = 0.0f;
        if (j < H_) {
            int row = g * H_ + j;
            a  = s * W_hh[row * H_ + 2 * m];
            bb = s * W_hh[row * H_ + 2 * m + 1];
        }
        half2v hv;
        hv.x = (_Float16)a;
        hv.y = (_Float16)bb;
        wpk[p] = __builtin_bit_cast(unsigned, hv);
    }
    for (int p = tid; p < 4 * 64; p += stride) {
        int j = p & 63;
        int g = p >> 6;
        float s = (g == 2) ? (2.0f * LOG2E) : (-LOG2E);
        float wi = 0.0f, bb = 0.0f;
        if (j < H_) {
            int row = g * H_ + j;
            wi = s * W_ih[row];
            bb = s * (b_ih[row] + b_hh[row]);
        }
        wih_pk[p] = wi;
        bias_pk[p] = bb;
    }
}

__global__
__attribute__((amdgpu_flat_work_group_size(64 * WPB, 64 * WPB)))
__attribute__((amdgpu_waves_per_eu(2, 2)))
void lstm_main(const float* __restrict__ x, const float* __restrict__ h0,
               const float* __restrict__ c0, const float* __restrict__ fc_w,
               const float* __restrict__ fc_b, const unsigned* __restrict__ wpk,
               const float* __restrict__ wih_pk, const float* __restrict__ bias_pk,
               float* __restrict__ out)
{
    const int tid = threadIdx.x;
    const int j   = tid & 63;
    const int wid = __builtin_amdgcn_readfirstlane(tid >> 6);
    const int b   = blockIdx.x * WPB + wid;

    // per-wave slice: no inter-wave sharing, no barriers anywhere.
    __shared__ unsigned hs16[WPB][32];
    unsigned* __restrict__ myh = &hs16[wid][0];

    // Per-lane weights: 4 gates x 25 f16-pairs = 100 VGPRs, coalesced loads.
    half2v w0[25], w1[25], w2[25], w3[25];
    #pragma unroll
    for (int m = 0; m < 25; ++m) {
        w0[m] = __builtin_bit_cast(half2v, wpk[(0 * 25 + m) * 64 + j]);
        w1[m] = __builtin_bit_cast(half2v, wpk[(1 * 25 + m) * 64 + j]);
        w2[m] = __builtin_bit_cast(half2v, wpk[(2 * 25 + m) * 64 + j]);
        w3[m] = __builtin_bit_cast(half2v, wpk[(3 * 25 + m) * 64 + j]);
    }

    float wih0 = wih_pk[0 * 64 + j], wih1 = wih_pk[1 * 64 + j];
    float wih2 = wih_pk[2 * 64 + j], wih3 = wih_pk[3 * 64 + j];
    float bs0 = bias_pk[0 * 64 + j], bs1 = bias_pk[1 * 64 + j];
    float bs2 = bias_pk[2 * 64 + j], bs3 = bias_pk[3 * 64 + j];

    float h = (j < H_) ? h0[b * H_ + j] : 0.0f;
    float c = (j < H_) ? c0[b * H_ + j] : 0.0f;

    // publish initial h pairs: even lane 2m packs (h[2m], h[2m+1]) -> slot m.
    // Single wave owns this slice: LDS is in-order per wave, no barrier.
    {
        int hn_ = __builtin_amdgcn_update_dpp(0, __builtin_bit_cast(int, h),
                                              0xB1, 0xF, 0xF, true);
        unsigned hpk = __builtin_bit_cast(unsigned,
            __builtin_amdgcn_cvt_pkrtz(h, __builtin_bit_cast(float, hn_)));
        if ((j & 1) == 0 && j < H_) myh[j >> 1] = hpk;
    }
    unsigned hp[25];
    #pragma unroll
    for (int m = 0; m < 25; ++m) hp[m] = myh[m];

    const float* __restrict__ xrow = x + b * S_;
    float xt = xrow[0];

    for (int s = 0; s < S_; ++s) {
        int sn = s + 1 < S_ ? s + 1 : S_ - 1;
        float xt_n = xrow[sn];

        float a0 = __builtin_fmaf(xt, wih0, bs0);
        float a1 = __builtin_fmaf(xt, wih1, bs1);
        float a2 = __builtin_fmaf(xt, wih2, bs2);
        float a3 = __builtin_fmaf(xt, wih3, bs3);

        #pragma unroll
        for (int m = 0; m < 25; ++m) {
            half2v hm = __builtin_bit_cast(half2v, hp[m]);
            a0 = __builtin_amdgcn_fdot2(hm, w0[m], a0, false);
            a1 = __builtin_amdgcn_fdot2(hm, w1[m], a1, false);
            a2 = __builtin_amdgcn_fdot2(hm, w2[m], a2, false);
            a3 = __builtin_amdgcn_fdot2(hm, w3[m], a3, false);
        }
        // a0..a3: i,f,g,o gate args, activation scales pre-folded.
        float ei = ex2_(a0); float si = rcp_(1.0f + ei);          // sigmoid(i)
        float ef = ex2_(a1); float sf = rcp_(1.0f + ef);          // sigmoid(f)
        float eg = ex2_(a2);
        float tg = __builtin_fmaf(-2.0f, rcp_(1.0f + eg), 1.0f);  // tanh(g)
        float eo = ex2_(a3); float so = rcp_(1.0f + eo);          // sigmoid(o)

        c = __builtin_fmaf(sf, c, si * tg);
        float ec = ex2_((2.0f * LOG2E) * c);
        float tc = __builtin_fmaf(-2.0f, rcp_(1.0f + ec), 1.0f);  // tanh(c)
        h = so * tc;

        // publish next h pairs (DPP + pkrtz + masked write), then re-read the
        // 25 uniform words; latency fills from the sibling wave on this SIMD.
        int hn_ = __builtin_amdgcn_update_dpp(0, __builtin_bit_cast(int, h),
                                              0xB1, 0xF, 0xF, true);
        unsigned hpk = __builtin_bit_cast(unsigned,
            __builtin_amdgcn_cvt_pkrtz(h, __builtin_bit_cast(float, hn_)));
        if ((j & 1) == 0 && j < H_) myh[j >> 1] = hpk;
        #pragma unroll
        for (int m = 0; m < 25; ++m) hp[m] = myh[m];

        xt = xt_n;
    }

    // outputs: [out (B,1)] [h_n (1,B,H)] [c_n (1,B,H)] concatenated
    if (j < H_) {
        out[B_ + b * H_ + j]           = h;
        out[B_ + B_ * H_ + b * H_ + j] = c;
    }
    float p = (j < H_) ? h * fc_w[j] : 0.0f;
    #pragma unroll
    for (int off = 32; off > 0; off >>= 1) p += __shfl_xor(p, off);
    if (j == 0) out[b] = p + fc_b[0];
}

extern "C" void kernel_launch(void* const* d_in, const int* in_sizes, int n_in,
                              void* d_out, int out_size, void* d_ws, size_t ws_size,
                              hipStream_t stream)
{
    const float* x    = (const float*)d_in[0];
    const float* h0   = (const float*)d_in[1];
    const float* c0   = (const float*)d_in[2];
    const float* W_ih = (const float*)d_in[3];
    const float* W_hh = (const float*)d_in[4];
    const float* b_ih = (const float*)d_in[5];
    const float* b_hh = (const float*)d_in[6];
    const float* fc_w = (const float*)d_in[7];
    const float* fc_b = (const float*)d_in[8];
    float* out = (float*)d_out;

    unsigned* wpk  = (unsigned*)d_ws;                               // 6400 u32 = 25.6 KB
    float* wih_pk  = (float*)((char*)d_ws + 6400 * 4);              // 256 f32
    float* bias_pk = (float*)((char*)d_ws + 6400 * 4 + 256 * 4);    // 256 f32

    lstm_pack<<<16, 256, 0, stream>>>(W_ih, W_hh, b_ih, b_hh, wpk, wih_pk, bias_pk);
    lstm_main<<<B_ / WPB, 64 * WPB, 0, stream>>>(x, h0, c0, fc_w, fc_b,
                                                 wpk, wih_pk, bias_pk, out);
}